// Round 15
// baseline (923.151 us; speedup 1.0000x reference)
//
#include <hip/hip_runtime.h>
#include <stdint.h>

// L=512, B=32, D=H=256
// Workspace (float offsets into 64MB d_ws):
//   Eq  f16[16384*256] @ 0         (8.4 MB)
//   Ev  f16[16384*256] @ 2097152
//   VT  f16[32][256][512] @ 4194304  (v transposed per batch, f16)
//   S   f32[32*512*512] @ 6291456
//   C   f32[16384*256] @ 0          (reuse Eq+Ev, dead after score)
//   Gi2 f16[16384*768] @ 6291456    (reuse S, dead after ctxm)

#define C2    2.8853900817779268f   // 2*log2(e)
#define LOG2E 1.4426950408889634f

typedef __fp16 f16x2 __attribute__((ext_vector_type(2)));
typedef __fp16 f16x4_t __attribute__((ext_vector_type(4)));
typedef __fp16 f16x8 __attribute__((ext_vector_type(8)));
typedef float f32x4 __attribute__((ext_vector_type(4)));

static __device__ __forceinline__ float rcp_f(float x)  { return __builtin_amdgcn_rcpf(x); }
static __device__ __forceinline__ float exp2_f(float x) { return __builtin_amdgcn_exp2f(x); }
#if __has_builtin(__builtin_amdgcn_rcph)
static __device__ __forceinline__ __fp16 rcph(__fp16 x) {
  return (__fp16)__builtin_amdgcn_rcph((_Float16)x);
}
#else
static __device__ __forceinline__ __fp16 rcph(__fp16 x) {
  return (__fp16)__builtin_amdgcn_rcpf((float)x);
}
#endif
static __device__ __forceinline__ float dot2f(f16x2 a, f16x2 b, float c) {
  return __builtin_amdgcn_fdot2(a, b, c, false);
}
static __device__ __forceinline__ f16x8 cvt8(float4 a, float4 b) {
  f16x8 f;
  f[0] = (__fp16)a.x; f[1] = (__fp16)a.y; f[2] = (__fp16)a.z; f[3] = (__fp16)a.w;
  f[4] = (__fp16)b.x; f[5] = (__fp16)b.y; f[6] = (__fp16)b.z; f[7] = (__fp16)b.w;
  return f;
}

// Fragment conventions (verified end-to-end):
//   A-frag: lane(col=lane&15, quad=lane>>4) holds A[m=col][k=quad*8+jj]
//   B-frag: lane holds B[k=quad*8+jj][n=col]
//   C/D:    row(m)=quad*4+reg, col(n)=lane&15

// ---------------------------------------------------------------------------
// Fused projections -> f16 with exponent clamp to f16-normal range.
// ---------------------------------------------------------------------------
__global__ __launch_bounds__(256) void proj_k(
    const float* __restrict__ v, const float* __restrict__ Wp,
    const float* __restrict__ Wp_, __fp16* __restrict__ Eq,
    __fp16* __restrict__ Ev)
{
  __shared__ __align__(16) __fp16 As[64][40];
  __shared__ __align__(16) __fp16 Wqs[64][40];
  __shared__ __align__(16) __fp16 Wvs[64][40];
  const int t = threadIdx.x, wave = t >> 6, lane = t & 63;
  const int quad = lane >> 4, col = lane & 15;
  const int n0 = blockIdx.x * 64, m0 = blockIdx.y * 64;
  const int srow = t >> 2, skq = t & 3;

  f32x4 accq[4], accv[4];
#pragma unroll
  for (int nt = 0; nt < 4; ++nt) {
    accq[nt] = (f32x4){0.f, 0.f, 0.f, 0.f};
    accv[nt] = (f32x4){0.f, 0.f, 0.f, 0.f};
  }

  for (int kc = 0; kc < 8; ++kc) {
    const int k0 = kc * 32;
    {
      const float4* ap = (const float4*)&v[(size_t)(m0 + srow) * 256 + k0 + skq * 8];
      *(f16x8*)&As[srow][skq * 8] = cvt8(ap[0], ap[1]);
      const float4* qp = (const float4*)&Wp[(size_t)(n0 + srow) * 256 + k0 + skq * 8];
      *(f16x8*)&Wqs[srow][skq * 8] = cvt8(qp[0], qp[1]);
      const float4* vp = (const float4*)&Wp_[(size_t)(n0 + srow) * 256 + k0 + skq * 8];
      *(f16x8*)&Wvs[srow][skq * 8] = cvt8(vp[0], vp[1]);
    }
    __syncthreads();
    f16x8 a = *(const f16x8*)&As[wave * 16 + col][quad * 8];
#pragma unroll
    for (int nt = 0; nt < 4; ++nt) {
      f16x8 bq = *(const f16x8*)&Wqs[nt * 16 + col][quad * 8];
      f16x8 bv = *(const f16x8*)&Wvs[nt * 16 + col][quad * 8];
      accq[nt] = __builtin_amdgcn_mfma_f32_16x16x32_f16(a, bq, accq[nt], 0, 0, 0);
      accv[nt] = __builtin_amdgcn_mfma_f32_16x16x32_f16(a, bv, accv[nt], 0, 0, 0);
    }
    __syncthreads();
  }

#pragma unroll
  for (int nt = 0; nt < 4; ++nt)
#pragma unroll
    for (int r = 0; r < 4; ++r) {
      size_t m = m0 + wave * 16 + quad * 4 + r;
      size_t n = n0 + nt * 16 + col;
      float eq = C2 * accq[nt][r], ev = C2 * accv[nt][r];
      eq = fminf(fmaxf(eq, -14.f), 15.5f);
      ev = fminf(fmaxf(ev, -14.f), 15.5f);
      Eq[m * 256 + n] = (__fp16)exp2_f(eq);
      Ev[m * 256 + n] = (__fp16)exp2_f(ev);
    }
}

// ---------------------------------------------------------------------------
// v transpose: VT[b][d][l] (f16) from v[l][b][d] (f32). 32x32 LDS tiles.
// grid (8 d-tiles, 16 l-tiles, 32 b), block 256.
// ---------------------------------------------------------------------------
__global__ __launch_bounds__(256) void vt_k(
    const float* __restrict__ v, __fp16* __restrict__ VT)
{
  __shared__ float Ts[32][33];
  const int t = threadIdx.x;
  const int d0 = blockIdx.x * 32, l0 = blockIdx.y * 32, b = blockIdx.z;
  {
    int lrow = t >> 3, dq = t & 7;
    float4 a = *(const float4*)&v[((size_t)(l0 + lrow) * 32 + b) * 256 + d0 + dq * 4];
    Ts[dq * 4 + 0][lrow] = a.x; Ts[dq * 4 + 1][lrow] = a.y;
    Ts[dq * 4 + 2][lrow] = a.z; Ts[dq * 4 + 3][lrow] = a.w;
  }
  __syncthreads();
  {
    int drow = t >> 3, lq = t & 7;
    f16x4_t o;
#pragma unroll
    for (int e = 0; e < 4; ++e) o[e] = (__fp16)Ts[drow][lq * 4 + e];
    *(f16x4_t*)&VT[((size_t)b * 256 + d0 + drow) * 512 + l0 + lq * 4] = o;
  }
}

// ---------------------------------------------------------------------------
// Packed-f16 score: S[b][i][l] = -2 * sum_h V[b][h] * rcp(1 + Eq*Ev).
// grid (16 l-tiles, 8 i-tiles, 32 b), block 256 (tx=16 l, ty=16 i).
// ---------------------------------------------------------------------------
__global__ __launch_bounds__(256) void score_k(
    const __fp16* __restrict__ Eq, const __fp16* __restrict__ Ev,
    const float* __restrict__ Vvec, float* __restrict__ S)
{
  __shared__ __align__(16) __fp16 Eqs[64][72];
  __shared__ __align__(16) __fp16 Evs[32][72];
  __shared__ __align__(16) __fp16 Vs[256];
  const int t = threadIdx.x;
  const int tx = t & 15, ty = t >> 4;
  const int l0 = blockIdx.x * 32;
  const int i0 = blockIdx.y * 64;
  const int b  = blockIdx.z;

  Vs[t] = (__fp16)(-2.0f * Vvec[b * 256 + t]);
  float acc[4][2] = {};
  const f16x2 one2 = {(__fp16)1.f, (__fp16)1.f};

  for (int st = 0; st < 4; ++st) {
    const int h0 = st * 64;
#pragma unroll
    for (int s = 0; s < 2; ++s) {
      int f = t + s * 256;
      int row = f >> 3, cq = f & 7;
      *(f16x8*)&Eqs[row][cq * 8] =
          *(const f16x8*)&Eq[((size_t)(i0 + row) * 32 + b) * 256 + h0 + cq * 8];
    }
    {
      int row = t >> 3, cq = t & 7;
      *(f16x8*)&Evs[row][cq * 8] =
          *(const f16x8*)&Ev[((size_t)(l0 + row) * 32 + b) * 256 + h0 + cq * 8];
    }
    __syncthreads();

#pragma unroll
    for (int k8 = 0; k8 < 8; ++k8) {
      f16x8 vh8 = *(const f16x8*)&Vs[h0 + k8 * 8];
      f16x8 ev80 = *(const f16x8*)&Evs[tx][k8 * 8];
      f16x8 ev81 = *(const f16x8*)&Evs[tx + 16][k8 * 8];
      f16x8 eq8[4];
#pragma unroll
      for (int r = 0; r < 4; ++r)
        eq8[r] = *(const f16x8*)&Eqs[ty * 4 + r][k8 * 8];
#pragma unroll
      for (int q = 0; q < 4; ++q) {
        f16x2 vh2 = {vh8[q * 2], vh8[q * 2 + 1]};
        f16x2 e0  = {ev80[q * 2], ev80[q * 2 + 1]};
        f16x2 e1  = {ev81[q * 2], ev81[q * 2 + 1]};
#pragma unroll
        for (int r = 0; r < 4; ++r) {
          f16x2 eq2 = {eq8[r][q * 2], eq8[r][q * 2 + 1]};
          f16x2 d0 = eq2 * e0 + one2;   // v_pk_fma_f16
          f16x2 d1 = eq2 * e1 + one2;
          f16x2 r0 = {rcph(d0[0]), rcph(d0[1])};
          f16x2 r1 = {rcph(d1[0]), rcph(d1[1])};
          acc[r][0] = dot2f(vh2, r0, acc[r][0]);
          acc[r][1] = dot2f(vh2, r1, acc[r][1]);
        }
      }
    }
    __syncthreads();
  }

#pragma unroll
  for (int r = 0; r < 4; ++r) {
    float* ps = &S[((size_t)b * 512 + i0 + ty * 4 + r) * 512 + l0];
    ps[tx]      = acc[r][0];
    ps[tx + 16] = acc[r][1];
  }
}

// ---------------------------------------------------------------------------
// In-place softmax over rows of 512. 4 rows/block (one wave each), float4.
// ---------------------------------------------------------------------------
__global__ __launch_bounds__(256) void softmax_k(float* __restrict__ S)
{
  const int wave = threadIdx.x >> 6, lane = threadIdx.x & 63;
  float* row = &S[((size_t)blockIdx.x * 4 + wave) * 512];
  float4 x0 = *(float4*)&row[lane * 4];
  float4 x1 = *(float4*)&row[256 + lane * 4];
  float m = fmaxf(fmaxf(fmaxf(x0.x, x0.y), fmaxf(x0.z, x0.w)),
                  fmaxf(fmaxf(x1.x, x1.y), fmaxf(x1.z, x1.w)));
#pragma unroll
  for (int o = 32; o; o >>= 1) m = fmaxf(m, __shfl_xor(m, o, 64));
  x0.x = exp2_f(LOG2E * (x0.x - m)); x0.y = exp2_f(LOG2E * (x0.y - m));
  x0.z = exp2_f(LOG2E * (x0.z - m)); x0.w = exp2_f(LOG2E * (x0.w - m));
  x1.x = exp2_f(LOG2E * (x1.x - m)); x1.y = exp2_f(LOG2E * (x1.y - m));
  x1.z = exp2_f(LOG2E * (x1.z - m)); x1.w = exp2_f(LOG2E * (x1.w - m));
  float sum = x0.x + x0.y + x0.z + x0.w + x1.x + x1.y + x1.z + x1.w;
#pragma unroll
  for (int o = 32; o; o >>= 1) sum += __shfl_xor(sum, o, 64);
  float inv = rcp_f(sum);
  x0.x *= inv; x0.y *= inv; x0.z *= inv; x0.w *= inv;
  x1.x *= inv; x1.y *= inv; x1.z *= inv; x1.w *= inv;
  *(float4*)&row[lane * 4] = x0;
  *(float4*)&row[256 + lane * 4] = x1;
}

// ---------------------------------------------------------------------------
// Context via MFMA: C[i][b][d] = sum_l Aw[b][i][l] * VT[b][d][l].
// B-operand staged from pre-transposed VT: clean f16x8 row copies (the old
// in-kernel transpose had 8-way bank-conflicted b16 stores: row stride 40
// halfs x 8-row spacing = 640 B = bank delta 0 mod 32).
// grid (4 d-tiles, 8 i-tiles, 32 b), block 256.
// ---------------------------------------------------------------------------
__global__ __launch_bounds__(256) void ctxm_k(
    const float* __restrict__ Aw, const __fp16* __restrict__ VT,
    float* __restrict__ C)
{
  __shared__ __align__(16) __fp16 As[64][40];
  __shared__ __align__(16) __fp16 Vs[64][40];
  const int t = threadIdx.x, wave = t >> 6, lane = t & 63;
  const int quad = lane >> 4, col = lane & 15;
  const int d0 = blockIdx.x * 64, i0 = blockIdx.y * 64, b = blockIdx.z;
  const int srow = t >> 2, skq = t & 3;

  f32x4 acc[4];
#pragma unroll
  for (int nt = 0; nt < 4; ++nt) acc[nt] = (f32x4){0.f, 0.f, 0.f, 0.f};

  for (int kc = 0; kc < 16; ++kc) {
    const int l0 = kc * 32;
    {
      const float4* ap =
          (const float4*)&Aw[((size_t)b * 512 + i0 + srow) * 512 + l0 + skq * 8];
      *(f16x8*)&As[srow][skq * 8] = cvt8(ap[0], ap[1]);
      // Vs[d-row][l-chunk]: 64 rows x 32 halfs, straight row copy from VT
      *(f16x8*)&Vs[srow][skq * 8] =
          *(const f16x8*)&VT[((size_t)b * 256 + d0 + srow) * 512 + l0 + skq * 8];
    }
    __syncthreads();
    f16x8 a = *(const f16x8*)&As[wave * 16 + col][quad * 8];
#pragma unroll
    for (int nt = 0; nt < 4; ++nt) {
      f16x8 bb = *(const f16x8*)&Vs[nt * 16 + col][quad * 8];
      acc[nt] = __builtin_amdgcn_mfma_f32_16x16x32_f16(a, bb, acc[nt], 0, 0, 0);
    }
    __syncthreads();
  }

#pragma unroll
  for (int nt = 0; nt < 4; ++nt)
#pragma unroll
    for (int r = 0; r < 4; ++r) {
      size_t i = i0 + wave * 16 + quad * 4 + r;
      size_t d = d0 + nt * 16 + col;
      C[(i * 32 + b) * 256 + d] = acc[nt][r];
    }
}

// ---------------------------------------------------------------------------
// Gi2 = f16( C @ Wih^T + bih (+bhh for gates r,z) ). M=16384, N=768, K=256.
// ---------------------------------------------------------------------------
__global__ __launch_bounds__(256) void gi_k(
    const float* __restrict__ A, const float* __restrict__ W,
    const float* __restrict__ bih, const float* __restrict__ bhh,
    __fp16* __restrict__ G)
{
  __shared__ __align__(16) __fp16 As[64][40];
  __shared__ __align__(16) __fp16 Ws[64][40];
  const int t = threadIdx.x, wave = t >> 6, lane = t & 63;
  const int quad = lane >> 4, col = lane & 15;
  const int n0 = blockIdx.x * 64, m0 = blockIdx.y * 64;
  const int srow = t >> 2, skq = t & 3;

  f32x4 acc[4];
#pragma unroll
  for (int nt = 0; nt < 4; ++nt) acc[nt] = (f32x4){0.f, 0.f, 0.f, 0.f};

  for (int kc = 0; kc < 8; ++kc) {
    const int k0 = kc * 32;
    {
      const float4* ap = (const float4*)&A[(size_t)(m0 + srow) * 256 + k0 + skq * 8];
      *(f16x8*)&As[srow][skq * 8] = cvt8(ap[0], ap[1]);
      const float4* wp = (const float4*)&W[(size_t)(n0 + srow) * 256 + k0 + skq * 8];
      *(f16x8*)&Ws[srow][skq * 8] = cvt8(wp[0], wp[1]);
    }
    __syncthreads();
    f16x8 a = *(const f16x8*)&As[wave * 16 + col][quad * 8];
#pragma unroll
    for (int nt = 0; nt < 4; ++nt) {
      f16x8 b = *(const f16x8*)&Ws[nt * 16 + col][quad * 8];
      acc[nt] = __builtin_amdgcn_mfma_f32_16x16x32_f16(a, b, acc[nt], 0, 0, 0);
    }
    __syncthreads();
  }

#pragma unroll
  for (int nt = 0; nt < 4; ++nt) {
    int n = n0 + nt * 16 + col;
    float bias = bih[n] + (n < 512 ? bhh[n] : 0.f);
#pragma unroll
    for (int r = 0; r < 4; ++r) {
      size_t m = m0 + wave * 16 + quad * 4 + r;
      G[m * 768 + n] = (__fp16)(acc[nt][r] + bias);
    }
  }
}

// ---------------------------------------------------------------------------
// MFMA GRU, one batch per block (32 blocks x 512 threads). R8/R11 form:
// ~71% of the per-SIMD MFMA-pipe floor; tail structural (R13 falsified
// the vmcnt-drain theory).
// ---------------------------------------------------------------------------
__global__ __launch_bounds__(512, 1) void gru_k(
    const __fp16* __restrict__ Gi2, const float* __restrict__ Whh,
    const float* __restrict__ bhh, const float* __restrict__ h0,
    float* __restrict__ out)
{
  __shared__ __align__(16) __fp16 hA[2][256];
  const int t = threadIdx.x, wave = t >> 6, lane = t & 63;
  const int quad = lane >> 4, col = lane & 15;
  const int b = blockIdx.x;
  const int jw = wave * 32;

  f16x8 Bf[2][3][8];
#pragma unroll
  for (int p = 0; p < 2; ++p)
#pragma unroll
    for (int g = 0; g < 3; ++g) {
      const float* wrow = &Whh[(size_t)(g * 256 + jw + p * 16 + col) * 256];
#pragma unroll
      for (int kk = 0; kk < 8; ++kk) {
        const float4* wp = (const float4*)&wrow[kk * 32 + quad * 8];
        Bf[p][g][kk] = cvt8(wp[0], wp[1]);
      }
    }

  float hold[2];
  float bn[2];
#pragma unroll
  for (int p = 0; p < 2; ++p) {
    int j = jw + p * 16 + col;
    bn[p] = bhh[512 + j];
    float h = h0[(size_t)b * 256 + j];
    hold[p] = h;
    if (quad == 0) hA[0][j] = (__fp16)h;
  }
  __syncthreads();

  __fp16 gcur[2][3];
#pragma unroll
  for (int p = 0; p < 2; ++p)
#pragma unroll
    for (int g = 0; g < 3; ++g)
      gcur[p][g] = Gi2[(size_t)b * 768 + g * 256 + jw + p * 16 + col];

  for (int i = 0; i < 512; ++i) {
    __fp16 gnext[2][3];
    {
      int ip = (i + 1 < 512) ? (i + 1) : 511;
#pragma unroll
      for (int p = 0; p < 2; ++p)
#pragma unroll
        for (int g = 0; g < 3; ++g)
          gnext[p][g] =
              Gi2[(size_t)(ip * 32 + b) * 768 + g * 256 + jw + p * 16 + col];
    }

    f32x4 acc[2][3];
#pragma unroll
    for (int p = 0; p < 2; ++p)
#pragma unroll
      for (int g = 0; g < 3; ++g)
        acc[p][g] = (f32x4){0.f, 0.f, 0.f, 0.f};

    const __fp16* hbuf = hA[i & 1];
#pragma unroll
    for (int kk = 0; kk < 8; ++kk) {
      f16x8 a = *(const f16x8*)&hbuf[kk * 32 + quad * 8];
#pragma unroll
      for (int p = 0; p < 2; ++p)
#pragma unroll
        for (int g = 0; g < 3; ++g)
          acc[p][g] = __builtin_amdgcn_mfma_f32_16x16x32_f16(
              a, Bf[p][g][kk], acc[p][g], 0, 0, 0);
    }

    __fp16* hnext = hA[(i + 1) & 1];
#pragma unroll
    for (int p = 0; p < 2; ++p) {
      int j = jw + p * 16 + col;
      float rr = rcp_f(1.f + exp2_f(-LOG2E * ((float)gcur[p][0] + acc[p][0][0])));
      float zz = rcp_f(1.f + exp2_f(-LOG2E * ((float)gcur[p][1] + acc[p][1][0])));
      float na = fmaf(rr, acc[p][2][0] + bn[p], (float)gcur[p][2]);
      float nn = fmaf(-2.f, rcp_f(1.f + exp2_f(C2 * na)), 1.f);
      float h = fmaf(zz, hold[p] - nn, nn);
      hold[p] = h;
      if (quad == 0) {
        out[((size_t)i * 32 + b) * 256 + j] = h;
        hnext[j] = (__fp16)h;
      }
    }
#pragma unroll
    for (int p = 0; p < 2; ++p)
#pragma unroll
      for (int g = 0; g < 3; ++g) gcur[p][g] = gnext[p][g];
    __syncthreads();
  }
}

// ---------------------------------------------------------------------------
extern "C" void kernel_launch(void* const* d_in, const int* in_sizes, int n_in,
                              void* d_out, int out_size, void* d_ws, size_t ws_size,
                              hipStream_t stream)
{
  const float* v   = (const float*)d_in[0];
  const float* h0  = (const float*)d_in[1];
  const float* Vv  = (const float*)d_in[2];
  const float* Wp  = (const float*)d_in[3];
  const float* Wp_ = (const float*)d_in[4];
  const float* Wih = (const float*)d_in[5];
  const float* Whh = (const float*)d_in[6];
  const float* bih = (const float*)d_in[7];
  const float* bhh = (const float*)d_in[8];
  float* out = (float*)d_out;
  float* ws  = (float*)d_ws;

  __fp16* Eq  = (__fp16*)ws;
  __fp16* Ev  = (__fp16*)(ws + 2097152);
  __fp16* VT  = (__fp16*)(ws + 4194304);
  float*  S   = ws + 6291456;
  float*  C   = ws;                        // reuse Eq+Ev (dead after score)
  __fp16* Gi2 = (__fp16*)(ws + 6291456);   // reuse S (dead after ctxm)

  proj_k<<<dim3(4, 256), 256, 0, stream>>>(v, Wp, Wp_, Eq, Ev);
  vt_k<<<dim3(8, 16, 32), 256, 0, stream>>>(v, VT);
  score_k<<<dim3(16, 8, 32), 256, 0, stream>>>(Eq, Ev, Vv, S);
  softmax_k<<<4096, 256, 0, stream>>>(S);
  ctxm_k<<<dim3(4, 8, 32), 256, 0, stream>>>(S, VT, C);
  gi_k<<<dim3(12, 256), 256, 0, stream>>>(C, Wih, bih, bhh, Gi2);
  gru_k<<<32, 512, 0, stream>>>(Gi2, Whh, bhh, h0, out);
}

// Round 16
// 918.719 us; speedup vs baseline: 1.0048x; 1.0048x over previous
//
#include <hip/hip_runtime.h>
#include <stdint.h>

// L=512, B=32, D=H=256
// Workspace (float offsets into 64MB d_ws):
//   Eq  f16[16384*256] @ 0
//   Ev  f16[16384*256] @ 2097152
//   VT  f16[32][256][512] @ 4194304
//   S   f32[32*512*512] @ 6291456   (raw scores; softmax fused into ctxsm_k)
//   C   f32[16384*256] @ 0          (reuse Eq+Ev, dead after score)
//   Gi2 f16[16384*768] @ 6291456    (reuse S, dead after ctxsm)

#define C2    2.8853900817779268f   // 2*log2(e)
#define LOG2E 1.4426950408889634f

typedef __fp16 f16x2 __attribute__((ext_vector_type(2)));
typedef __fp16 f16x4_t __attribute__((ext_vector_type(4)));
typedef __fp16 f16x8 __attribute__((ext_vector_type(8)));
typedef float f32x4 __attribute__((ext_vector_type(4)));

static __device__ __forceinline__ float rcp_f(float x)  { return __builtin_amdgcn_rcpf(x); }
static __device__ __forceinline__ float exp2_f(float x) { return __builtin_amdgcn_exp2f(x); }
#if __has_builtin(__builtin_amdgcn_rcph)
static __device__ __forceinline__ __fp16 rcph(__fp16 x) {
  return (__fp16)__builtin_amdgcn_rcph((_Float16)x);
}
#else
static __device__ __forceinline__ __fp16 rcph(__fp16 x) {
  return (__fp16)__builtin_amdgcn_rcpf((float)x);
}
#endif
static __device__ __forceinline__ float dot2f(f16x2 a, f16x2 b, float c) {
  return __builtin_amdgcn_fdot2(a, b, c, false);
}
static __device__ __forceinline__ f16x8 cvt8(float4 a, float4 b) {
  f16x8 f;
  f[0] = (__fp16)a.x; f[1] = (__fp16)a.y; f[2] = (__fp16)a.z; f[3] = (__fp16)a.w;
  f[4] = (__fp16)b.x; f[5] = (__fp16)b.y; f[6] = (__fp16)b.z; f[7] = (__fp16)b.w;
  return f;
}

// Fragment conventions (verified end-to-end):
//   A-frag: lane(col=lane&15, quad=lane>>4) holds A[m=col][k=quad*8+jj]
//   B-frag: lane holds B[k=quad*8+jj][n=col]
//   C/D:    row(m)=quad*4+reg, col(n)=lane&15

// ---------------------------------------------------------------------------
// Fused projections -> f16 with exponent clamp to f16-normal range.
// ---------------------------------------------------------------------------
__global__ __launch_bounds__(256) void proj_k(
    const float* __restrict__ v, const float* __restrict__ Wp,
    const float* __restrict__ Wp_, __fp16* __restrict__ Eq,
    __fp16* __restrict__ Ev)
{
  __shared__ __align__(16) __fp16 As[64][40];
  __shared__ __align__(16) __fp16 Wqs[64][40];
  __shared__ __align__(16) __fp16 Wvs[64][40];
  const int t = threadIdx.x, wave = t >> 6, lane = t & 63;
  const int quad = lane >> 4, col = lane & 15;
  const int n0 = blockIdx.x * 64, m0 = blockIdx.y * 64;
  const int srow = t >> 2, skq = t & 3;

  f32x4 accq[4], accv[4];
#pragma unroll
  for (int nt = 0; nt < 4; ++nt) {
    accq[nt] = (f32x4){0.f, 0.f, 0.f, 0.f};
    accv[nt] = (f32x4){0.f, 0.f, 0.f, 0.f};
  }

  for (int kc = 0; kc < 8; ++kc) {
    const int k0 = kc * 32;
    {
      const float4* ap = (const float4*)&v[(size_t)(m0 + srow) * 256 + k0 + skq * 8];
      *(f16x8*)&As[srow][skq * 8] = cvt8(ap[0], ap[1]);
      const float4* qp = (const float4*)&Wp[(size_t)(n0 + srow) * 256 + k0 + skq * 8];
      *(f16x8*)&Wqs[srow][skq * 8] = cvt8(qp[0], qp[1]);
      const float4* vp = (const float4*)&Wp_[(size_t)(n0 + srow) * 256 + k0 + skq * 8];
      *(f16x8*)&Wvs[srow][skq * 8] = cvt8(vp[0], vp[1]);
    }
    __syncthreads();
    f16x8 a = *(const f16x8*)&As[wave * 16 + col][quad * 8];
#pragma unroll
    for (int nt = 0; nt < 4; ++nt) {
      f16x8 bq = *(const f16x8*)&Wqs[nt * 16 + col][quad * 8];
      f16x8 bv = *(const f16x8*)&Wvs[nt * 16 + col][quad * 8];
      accq[nt] = __builtin_amdgcn_mfma_f32_16x16x32_f16(a, bq, accq[nt], 0, 0, 0);
      accv[nt] = __builtin_amdgcn_mfma_f32_16x16x32_f16(a, bv, accv[nt], 0, 0, 0);
    }
    __syncthreads();
  }

#pragma unroll
  for (int nt = 0; nt < 4; ++nt)
#pragma unroll
    for (int r = 0; r < 4; ++r) {
      size_t m = m0 + wave * 16 + quad * 4 + r;
      size_t n = n0 + nt * 16 + col;
      float eq = C2 * accq[nt][r], ev = C2 * accv[nt][r];
      eq = fminf(fmaxf(eq, -14.f), 15.5f);
      ev = fminf(fmaxf(ev, -14.f), 15.5f);
      Eq[m * 256 + n] = (__fp16)exp2_f(eq);
      Ev[m * 256 + n] = (__fp16)exp2_f(ev);
    }
}

// ---------------------------------------------------------------------------
// v transpose: VT[b][d][l] (f16) from v[l][b][d] (f32). 32x32 LDS tiles.
// ---------------------------------------------------------------------------
__global__ __launch_bounds__(256) void vt_k(
    const float* __restrict__ v, __fp16* __restrict__ VT)
{
  __shared__ float Ts[32][33];
  const int t = threadIdx.x;
  const int d0 = blockIdx.x * 32, l0 = blockIdx.y * 32, b = blockIdx.z;
  {
    int lrow = t >> 3, dq = t & 7;
    float4 a = *(const float4*)&v[((size_t)(l0 + lrow) * 32 + b) * 256 + d0 + dq * 4];
    Ts[dq * 4 + 0][lrow] = a.x; Ts[dq * 4 + 1][lrow] = a.y;
    Ts[dq * 4 + 2][lrow] = a.z; Ts[dq * 4 + 3][lrow] = a.w;
  }
  __syncthreads();
  {
    int drow = t >> 3, lq = t & 7;
    f16x4_t o;
#pragma unroll
    for (int e = 0; e < 4; ++e) o[e] = (__fp16)Ts[drow][lq * 4 + e];
    *(f16x4_t*)&VT[((size_t)b * 256 + d0 + drow) * 512 + l0 + lq * 4] = o;
  }
}

// ---------------------------------------------------------------------------
// Packed-f16 score: S[b][i][l] = -2 * sum_h V[b][h] * rcp(1 + Eq*Ev).
// ---------------------------------------------------------------------------
__global__ __launch_bounds__(256) void score_k(
    const __fp16* __restrict__ Eq, const __fp16* __restrict__ Ev,
    const float* __restrict__ Vvec, float* __restrict__ S)
{
  __shared__ __align__(16) __fp16 Eqs[64][72];
  __shared__ __align__(16) __fp16 Evs[32][72];
  __shared__ __align__(16) __fp16 Vs[256];
  const int t = threadIdx.x;
  const int tx = t & 15, ty = t >> 4;
  const int l0 = blockIdx.x * 32;
  const int i0 = blockIdx.y * 64;
  const int b  = blockIdx.z;

  Vs[t] = (__fp16)(-2.0f * Vvec[b * 256 + t]);
  float acc[4][2] = {};
  const f16x2 one2 = {(__fp16)1.f, (__fp16)1.f};

  for (int st = 0; st < 4; ++st) {
    const int h0 = st * 64;
#pragma unroll
    for (int s = 0; s < 2; ++s) {
      int f = t + s * 256;
      int row = f >> 3, cq = f & 7;
      *(f16x8*)&Eqs[row][cq * 8] =
          *(const f16x8*)&Eq[((size_t)(i0 + row) * 32 + b) * 256 + h0 + cq * 8];
    }
    {
      int row = t >> 3, cq = t & 7;
      *(f16x8*)&Evs[row][cq * 8] =
          *(const f16x8*)&Ev[((size_t)(l0 + row) * 32 + b) * 256 + h0 + cq * 8];
    }
    __syncthreads();

#pragma unroll
    for (int k8 = 0; k8 < 8; ++k8) {
      f16x8 vh8 = *(const f16x8*)&Vs[h0 + k8 * 8];
      f16x8 ev80 = *(const f16x8*)&Evs[tx][k8 * 8];
      f16x8 ev81 = *(const f16x8*)&Evs[tx + 16][k8 * 8];
      f16x8 eq8[4];
#pragma unroll
      for (int r = 0; r < 4; ++r)
        eq8[r] = *(const f16x8*)&Eqs[ty * 4 + r][k8 * 8];
#pragma unroll
      for (int q = 0; q < 4; ++q) {
        f16x2 vh2 = {vh8[q * 2], vh8[q * 2 + 1]};
        f16x2 e0  = {ev80[q * 2], ev80[q * 2 + 1]};
        f16x2 e1  = {ev81[q * 2], ev81[q * 2 + 1]};
#pragma unroll
        for (int r = 0; r < 4; ++r) {
          f16x2 eq2 = {eq8[r][q * 2], eq8[r][q * 2 + 1]};
          f16x2 d0 = eq2 * e0 + one2;   // v_pk_fma_f16
          f16x2 d1 = eq2 * e1 + one2;
          f16x2 r0 = {rcph(d0[0]), rcph(d0[1])};
          f16x2 r1 = {rcph(d1[0]), rcph(d1[1])};
          acc[r][0] = dot2f(vh2, r0, acc[r][0]);
          acc[r][1] = dot2f(vh2, r1, acc[r][1]);
        }
      }
    }
    __syncthreads();
  }

#pragma unroll
  for (int r = 0; r < 4; ++r) {
    float* ps = &S[((size_t)b * 512 + i0 + ty * 4 + r) * 512 + l0];
    ps[tx]      = acc[r][0];
    ps[tx + 16] = acc[r][1];
  }
}

// ---------------------------------------------------------------------------
// FUSED softmax + context: C[i][b][d] = sum_l softmax_l(S[b][i][:])[l] * VT[b][d][l].
// Block = (64-row i-tile, b): grid (8, 32) x 512 threads, d = full 256.
// Phase 1: per-row max & sum(exp2) over S (L2-resident), LDS 8-way reduce.
// Phase 2: MFMA over 16 l-chunks; softmax applied during A staging (f32 ->
// weight -> f16), numerically identical to the separate softmax_k path.
// ---------------------------------------------------------------------------
__global__ __launch_bounds__(512) void ctxsm_k(
    const float* __restrict__ S, const __fp16* __restrict__ VT,
    float* __restrict__ C)
{
  __shared__ __align__(16) __fp16 As[64][40];
  __shared__ __align__(16) __fp16 Vs[256][40];
  __shared__ float red[64][8];
  __shared__ float stat_m[64], stat_inv[64];
  const int t = threadIdx.x, wave = t >> 6, lane = t & 63;
  const int quad = lane >> 4, col = lane & 15;
  const int i0 = blockIdx.x * 64, b = blockIdx.y;
  const int mt = wave & 3, nh = wave >> 2;

  // ---- phase 1: row stats (row = t>>3, seg = t&7; 64 elems per thread) ----
  {
    const int row = t >> 3, seg = t & 7;
    const float* sp = &S[((size_t)b * 512 + i0 + row) * 512 + seg * 64];
    float m = -1e30f;
#pragma unroll
    for (int u = 0; u < 16; ++u) {
      float4 x = *(const float4*)&sp[u * 4];
      m = fmaxf(m, fmaxf(fmaxf(x.x, x.y), fmaxf(x.z, x.w)));
    }
    red[row][seg] = m;
    __syncthreads();
    if (seg == 0) {
      float mm = red[row][0];
#pragma unroll
      for (int u = 1; u < 8; ++u) mm = fmaxf(mm, red[row][u]);
      stat_m[row] = mm;
    }
    __syncthreads();
    float M = stat_m[row];
    float s = 0.f;
#pragma unroll
    for (int u = 0; u < 16; ++u) {
      float4 x = *(const float4*)&sp[u * 4];
      s += exp2_f(LOG2E * (x.x - M)) + exp2_f(LOG2E * (x.y - M)) +
           exp2_f(LOG2E * (x.z - M)) + exp2_f(LOG2E * (x.w - M));
    }
    red[row][seg] = s;
    __syncthreads();
    if (seg == 0) {
      float ss = red[row][0];
#pragma unroll
      for (int u = 1; u < 8; ++u) ss += red[row][u];
      stat_inv[row] = rcp_f(ss);
    }
    __syncthreads();
  }

  // ---- phase 2: MFMA with softmax applied at A staging ----
  f32x4 acc[8];
#pragma unroll
  for (int n = 0; n < 8; ++n) acc[n] = (f32x4){0.f, 0.f, 0.f, 0.f};

  for (int kc = 0; kc < 16; ++kc) {
    const int l0 = kc * 32;
    {
      // A: 64 rows x 32 l, 4 f32 each (row = t>>3, aq = t&7)
      int arow = t >> 3, aq = t & 7;
      float M = stat_m[arow], inv = stat_inv[arow];
      float4 x = *(const float4*)&S[((size_t)b * 512 + i0 + arow) * 512 + l0 + aq * 4];
      f16x4_t o;
      o[0] = (__fp16)(exp2_f(LOG2E * (x.x - M)) * inv);
      o[1] = (__fp16)(exp2_f(LOG2E * (x.y - M)) * inv);
      o[2] = (__fp16)(exp2_f(LOG2E * (x.z - M)) * inv);
      o[3] = (__fp16)(exp2_f(LOG2E * (x.w - M)) * inv);
      *(f16x4_t*)&As[arow][aq * 4] = o;
      // V: 256 rows x 32 l as f16x8 chunks (1024 chunks / 512 threads = 2)
#pragma unroll
      for (int s2 = 0; s2 < 2; ++s2) {
        int f = t + s2 * 512;
        int vrow = f >> 2, vq = f & 3;
        *(f16x8*)&Vs[vrow][vq * 8] =
            *(const f16x8*)&VT[((size_t)b * 256 + vrow) * 512 + l0 + vq * 8];
      }
    }
    __syncthreads();
    f16x8 a = *(const f16x8*)&As[mt * 16 + col][quad * 8];
#pragma unroll
    for (int n = 0; n < 8; ++n) {
      f16x8 vf = *(const f16x8*)&Vs[nh * 128 + n * 16 + col][quad * 8];
      acc[n] = __builtin_amdgcn_mfma_f32_16x16x32_f16(a, vf, acc[n], 0, 0, 0);
    }
    __syncthreads();
  }

#pragma unroll
  for (int n = 0; n < 8; ++n)
#pragma unroll
    for (int r = 0; r < 4; ++r) {
      size_t i = i0 + mt * 16 + quad * 4 + r;
      size_t d = nh * 128 + n * 16 + col;
      C[(i * 32 + b) * 256 + d] = acc[n][r];
    }
}

// ---------------------------------------------------------------------------
// Gi2 = f16( C @ Wih^T + bih (+bhh for gates r,z) ). M=16384, N=768, K=256.
// ---------------------------------------------------------------------------
__global__ __launch_bounds__(256) void gi_k(
    const float* __restrict__ A, const float* __restrict__ W,
    const float* __restrict__ bih, const float* __restrict__ bhh,
    __fp16* __restrict__ G)
{
  __shared__ __align__(16) __fp16 As[64][40];
  __shared__ __align__(16) __fp16 Ws[64][40];
  const int t = threadIdx.x, wave = t >> 6, lane = t & 63;
  const int quad = lane >> 4, col = lane & 15;
  const int n0 = blockIdx.x * 64, m0 = blockIdx.y * 64;
  const int srow = t >> 2, skq = t & 3;

  f32x4 acc[4];
#pragma unroll
  for (int nt = 0; nt < 4; ++nt) acc[nt] = (f32x4){0.f, 0.f, 0.f, 0.f};

  for (int kc = 0; kc < 8; ++kc) {
    const int k0 = kc * 32;
    {
      const float4* ap = (const float4*)&A[(size_t)(m0 + srow) * 256 + k0 + skq * 8];
      *(f16x8*)&As[srow][skq * 8] = cvt8(ap[0], ap[1]);
      const float4* wp = (const float4*)&W[(size_t)(n0 + srow) * 256 + k0 + skq * 8];
      *(f16x8*)&Ws[srow][skq * 8] = cvt8(wp[0], wp[1]);
    }
    __syncthreads();
    f16x8 a = *(const f16x8*)&As[wave * 16 + col][quad * 8];
#pragma unroll
    for (int nt = 0; nt < 4; ++nt) {
      f16x8 b = *(const f16x8*)&Ws[nt * 16 + col][quad * 8];
      acc[nt] = __builtin_amdgcn_mfma_f32_16x16x32_f16(a, b, acc[nt], 0, 0, 0);
    }
    __syncthreads();
  }

#pragma unroll
  for (int nt = 0; nt < 4; ++nt) {
    int n = n0 + nt * 16 + col;
    float bias = bih[n] + (n < 512 ? bhh[n] : 0.f);
#pragma unroll
    for (int r = 0; r < 4; ++r) {
      size_t m = m0 + wave * 16 + quad * 4 + r;
      G[m * 768 + n] = (__fp16)(acc[nt][r] + bias);
    }
  }
}

// ---------------------------------------------------------------------------
// MFMA GRU, one batch per block (32 blocks x 512 threads). R8/R11 form.
// ---------------------------------------------------------------------------
__global__ __launch_bounds__(512, 1) void gru_k(
    const __fp16* __restrict__ Gi2, const float* __restrict__ Whh,
    const float* __restrict__ bhh, const float* __restrict__ h0,
    float* __restrict__ out)
{
  __shared__ __align__(16) __fp16 hA[2][256];
  const int t = threadIdx.x, wave = t >> 6, lane = t & 63;
  const int quad = lane >> 4, col = lane & 15;
  const int b = blockIdx.x;
  const int jw = wave * 32;

  f16x8 Bf[2][3][8];
#pragma unroll
  for (int p = 0; p < 2; ++p)
#pragma unroll
    for (int g = 0; g < 3; ++g) {
      const float* wrow = &Whh[(size_t)(g * 256 + jw + p * 16 + col) * 256];
#pragma unroll
      for (int kk = 0; kk < 8; ++kk) {
        const float4* wp = (const float4*)&wrow[kk * 32 + quad * 8];
        Bf[p][g][kk] = cvt8(wp[0], wp[1]);
      }
    }

  float hold[2];
  float bn[2];
#pragma unroll
  for (int p = 0; p < 2; ++p) {
    int j = jw + p * 16 + col;
    bn[p] = bhh[512 + j];
    float h = h0[(size_t)b * 256 + j];
    hold[p] = h;
    if (quad == 0) hA[0][j] = (__fp16)h;
  }
  __syncthreads();

  __fp16 gcur[2][3];
#pragma unroll
  for (int p = 0; p < 2; ++p)
#pragma unroll
    for (int g = 0; g < 3; ++g)
      gcur[p][g] = Gi2[(size_t)b * 768 + g * 256 + jw + p * 16 + col];

  for (int i = 0; i < 512; ++i) {
    __fp16 gnext[2][3];
    {
      int ip = (i + 1 < 512) ? (i + 1) : 511;
#pragma unroll
      for (int p = 0; p < 2; ++p)
#pragma unroll
        for (int g = 0; g < 3; ++g)
          gnext[p][g] =
              Gi2[(size_t)(ip * 32 + b) * 768 + g * 256 + jw + p * 16 + col];
    }

    f32x4 acc[2][3];
#pragma unroll
    for (int p = 0; p < 2; ++p)
#pragma unroll
      for (int g = 0; g < 3; ++g)
        acc[p][g] = (f32x4){0.f, 0.f, 0.f, 0.f};

    const __fp16* hbuf = hA[i & 1];
#pragma unroll
    for (int kk = 0; kk < 8; ++kk) {
      f16x8 a = *(const f16x8*)&hbuf[kk * 32 + quad * 8];
#pragma unroll
      for (int p = 0; p < 2; ++p)
#pragma unroll
        for (int g = 0; g < 3; ++g)
          acc[p][g] = __builtin_amdgcn_mfma_f32_16x16x32_f16(
              a, Bf[p][g][kk], acc[p][g], 0, 0, 0);
    }

    __fp16* hnext = hA[(i + 1) & 1];
#pragma unroll
    for (int p = 0; p < 2; ++p) {
      int j = jw + p * 16 + col;
      float rr = rcp_f(1.f + exp2_f(-LOG2E * ((float)gcur[p][0] + acc[p][0][0])));
      float zz = rcp_f(1.f + exp2_f(-LOG2E * ((float)gcur[p][1] + acc[p][1][0])));
      float na = fmaf(rr, acc[p][2][0] + bn[p], (float)gcur[p][2]);
      float nn = fmaf(-2.f, rcp_f(1.f + exp2_f(C2 * na)), 1.f);
      float h = fmaf(zz, hold[p] - nn, nn);
      hold[p] = h;
      if (quad == 0) {
        out[((size_t)i * 32 + b) * 256 + j] = h;
        hnext[j] = (__fp16)h;
      }
    }
#pragma unroll
    for (int p = 0; p < 2; ++p)
#pragma unroll
      for (int g = 0; g < 3; ++g) gcur[p][g] = gnext[p][g];
    __syncthreads();
  }
}

// ---------------------------------------------------------------------------
extern "C" void kernel_launch(void* const* d_in, const int* in_sizes, int n_in,
                              void* d_out, int out_size, void* d_ws, size_t ws_size,
                              hipStream_t stream)
{
  const float* v   = (const float*)d_in[0];
  const float* h0  = (const float*)d_in[1];
  const float* Vv  = (const float*)d_in[2];
  const float* Wp  = (const float*)d_in[3];
  const float* Wp_ = (const float*)d_in[4];
  const float* Wih = (const float*)d_in[5];
  const float* Whh = (const float*)d_in[6];
  const float* bih = (const float*)d_in[7];
  const float* bhh = (const float*)d_in[8];
  float* out = (float*)d_out;
  float* ws  = (float*)d_ws;

  __fp16* Eq  = (__fp16*)ws;
  __fp16* Ev  = (__fp16*)(ws + 2097152);
  __fp16* VT  = (__fp16*)(ws + 4194304);
  float*  S   = ws + 6291456;
  float*  C   = ws;                        // reuse Eq+Ev (dead after score)
  __fp16* Gi2 = (__fp16*)(ws + 6291456);   // reuse S (dead after ctxsm)

  proj_k<<<dim3(4, 256), 256, 0, stream>>>(v, Wp, Wp_, Eq, Ev);
  vt_k<<<dim3(8, 16, 32), 256, 0, stream>>>(v, VT);
  score_k<<<dim3(16, 8, 32), 256, 0, stream>>>(Eq, Ev, Vv, S);
  ctxsm_k<<<dim3(8, 32), 512, 0, stream>>>(S, VT, C);
  gi_k<<<dim3(12, 256), 256, 0, stream>>>(C, Wih, bih, bhh, Gi2);
  gru_k<<<32, 512, 0, stream>>>(Gi2, Whh, bhh, h0, out);
}